// Round 1
// baseline (274.456 us; speedup 1.0000x reference)
//
#include <hip/hip_runtime.h>
#include <hip/hip_fp16.h>

#define B_ 64
#define T_ 2048
#define D_ 256
#define U_ 256
#define BM 64   // T rows per block in score kernel

typedef _Float16 half8 __attribute__((ext_vector_type(8)));
typedef _Float16 half4v __attribute__((ext_vector_type(4)));
typedef float    floatx4 __attribute__((ext_vector_type(4)));

// ---------------- Kernel 1: qb[b,u] = query[b]·W1[:,u] + W1_b[u] + W2_b[u] ----------------
__global__ void qproj_kernel(const float* __restrict__ query,
                             const float* __restrict__ W1_w,
                             const float* __restrict__ W1_b,
                             const float* __restrict__ W2_b,
                             float* __restrict__ qb) {
    __shared__ float qrow[D_];
    const int b = blockIdx.x;
    const int u = threadIdx.x;           // blockDim.x == 256 == U_
    qrow[u] = query[b * D_ + u];
    __syncthreads();
    float acc = W1_b[u] + W2_b[u];
#pragma unroll 8
    for (int d = 0; d < D_; ++d)
        acc += qrow[d] * W1_w[d * U_ + u];   // coalesced over u
    qb[b * U_ + u] = acc;
}

// ---------------- Kernel 2: w2t[u,d] = (fp16) W2[d,u] ----------------
__global__ void w2t_kernel(const float* __restrict__ W2_w, _Float16* __restrict__ w2t) {
    __shared__ float tile[32][33];
    const int tu = blockIdx.x & 7;       // u tile
    const int td = blockIdx.x >> 3;      // d tile
    const int c  = threadIdx.x & 31;
    const int r0 = threadIdx.x >> 5;     // 0..7
#pragma unroll
    for (int i = 0; i < 4; ++i) {
        int r = r0 + i * 8;
        tile[r][c] = W2_w[(td * 32 + r) * U_ + tu * 32 + c];   // coalesced over c(=u)
    }
    __syncthreads();
#pragma unroll
    for (int i = 0; i < 4; ++i) {
        int r = r0 + i * 8;              // u within tile
        w2t[(tu * 32 + r) * D_ + td * 32 + c] = (_Float16)tile[c][r];  // coalesced over c(=d)
    }
}

// ---------------- Kernel 3: scores[b,t] = tanh(qb[b]+values[b,t]·W2)·V_w ----------------
// grid (T/BM, B), 256 threads = 4 waves. Wave w owns U-chunk [w*64, w*64+64).
// B-fragments (W2) register-stationary per wave; values staged fp32->fp16 in LDS per 16-row tile.
__launch_bounds__(256, 2)
__global__ void score_kernel(const float* __restrict__ values,
                             const _Float16* __restrict__ w2t,
                             const float* __restrict__ qb,
                             const float* __restrict__ V_w,
                             float* __restrict__ scores) {
    constexpr int LDP = D_ + 8;                 // LDS row pitch (halves): breaks bank alignment
    __shared__ _Float16 lds_v[16 * LDP];        // one 16-row t-tile, fp16
    __shared__ float s_part[4][16];

    const int b    = blockIdx.y;
    const int tblk = blockIdx.x;
    const int tid  = threadIdx.x;
    const int wave = tid >> 6;
    const int lane = tid & 63;
    const int n16  = lane & 15;
    const int quad = lane >> 4;
    const int u0   = wave * 64;

    // --- W2 B-fragments, loaded once, register-stationary ---
    // B layout (16x16x32): lane holds B[k = quad*8+j][n = lane&15], j=0..7 contiguous in w2t.
    half8 bfrag[4][8];
#pragma unroll
    for (int ut = 0; ut < 4; ++ut) {
        const int u = u0 + ut * 16 + n16;
#pragma unroll
        for (int k = 0; k < 8; ++k)
            bfrag[ut][k] = *(const half8*)(w2t + u * D_ + k * 32 + quad * 8);
    }
    float qbv[4], vwv[4];
#pragma unroll
    for (int ut = 0; ut < 4; ++ut) {
        const int u = u0 + ut * 16 + n16;
        qbv[ut] = qb[b * U_ + u];
        vwv[ut] = V_w[u];
    }

    const float* vbase = values + (size_t)b * T_ * D_ + (size_t)tblk * BM * D_;

    for (int tt = 0; tt < 4; ++tt) {
        // --- stage 16 rows x 256 d: fp32 global -> fp16 LDS (4096 floats, 4 float4/thread) ---
        const float* src = vbase + tt * 16 * D_;
#pragma unroll
        for (int rep = 0; rep < 4; ++rep) {
            const int f   = tid + rep * 256;    // float4 index 0..1023
            const int row = f >> 6;
            const int dd  = (f & 63) * 4;
            floatx4 v = *(const floatx4*)(src + row * D_ + dd);
            half4v h;
            h.x = (_Float16)v.x; h.y = (_Float16)v.y;
            h.z = (_Float16)v.z; h.w = (_Float16)v.w;
            *(half4v*)(&lds_v[row * LDP + dd]) = h;
        }
        __syncthreads();

        // --- MFMA: Vp[16 x 64chunk] ---
        // A layout: lane holds A[m = lane&15][k = quad*8+j], contiguous in lds_v row.
        floatx4 acc[4] = {};
#pragma unroll
        for (int k = 0; k < 8; ++k) {
            half8 a = *(const half8*)(&lds_v[n16 * LDP + k * 32 + quad * 8]);
#pragma unroll
            for (int ut = 0; ut < 4; ++ut)
                acc[ut] = __builtin_amdgcn_mfma_f32_16x16x32_f16(a, bfrag[ut][k], acc[ut], 0, 0, 0);
        }

        // --- epilogue: tanh + dot with V_w, reduce over u ---
        // C/D layout: row = quad*4+reg, col(u) = lane&15.
        float part[4];
#pragma unroll
        for (int r = 0; r < 4; ++r) {
            float s = 0.f;
#pragma unroll
            for (int ut = 0; ut < 4; ++ut) {
                float x  = acc[ut][r] + qbv[ut];
                float e  = __expf(2.f * x);
                float th = 1.f - __fdividef(2.f, e + 1.f);   // tanh(x)
                s += th * vwv[ut];
            }
            part[r] = s;
        }
#pragma unroll
        for (int m = 1; m < 16; m <<= 1)
#pragma unroll
            for (int r = 0; r < 4; ++r)
                part[r] += __shfl_xor(part[r], m, 16);
        if (n16 == 0)
#pragma unroll
            for (int r = 0; r < 4; ++r)
                s_part[wave][quad * 4 + r] = part[r];
        __syncthreads();
        if (tid < 16) {
            float s = s_part[0][tid] + s_part[1][tid] + s_part[2][tid] + s_part[3][tid];
            scores[b * T_ + tblk * BM + tt * 16 + tid] = s;
        }
        __syncthreads();
    }
}

// ---------------- Kernel 4: softmax over T per batch ----------------
__global__ void softmax_kernel(const float* __restrict__ scores, float* __restrict__ attn) {
    const int b   = blockIdx.x;
    const int tid = threadIdx.x;      // 256 threads, 8 scores each
    const float* s = scores + b * T_;
    float v[8];
    float mx = -1e30f;
#pragma unroll
    for (int i = 0; i < 8; ++i) {
        v[i] = s[tid + i * 256];
        mx = fmaxf(mx, v[i]);
    }
    for (int m = 32; m >= 1; m >>= 1) mx = fmaxf(mx, __shfl_xor(mx, m, 64));
    __shared__ float wmax[4], wsum[4];
    const int wave = tid >> 6, lane = tid & 63;
    if (lane == 0) wmax[wave] = mx;
    __syncthreads();
    mx = fmaxf(fmaxf(wmax[0], wmax[1]), fmaxf(wmax[2], wmax[3]));
    float sum = 0.f;
#pragma unroll
    for (int i = 0; i < 8; ++i) { v[i] = __expf(v[i] - mx); sum += v[i]; }
    for (int m = 32; m >= 1; m >>= 1) sum += __shfl_xor(sum, m, 64);
    if (lane == 0) wsum[wave] = sum;
    __syncthreads();
    sum = wsum[0] + wsum[1] + wsum[2] + wsum[3];
    const float inv = 1.f / sum;
#pragma unroll
    for (int i = 0; i < 8; ++i) attn[b * T_ + tid + i * 256] = v[i] * inv;
}

// ---------------- Kernel 5: ctx[b,d] = sum_t attn[b,t]*values[b,t,d] ----------------
// grid (8, B): each block does a 256-row T chunk, float4 over D, atomicAdd partials.
__global__ void context_kernel(const float* __restrict__ values,
                               const float* __restrict__ attn,
                               float* __restrict__ ctx) {
    __shared__ float w[256];
    const int b     = blockIdx.y;
    const int chunk = blockIdx.x;
    const int tid   = threadIdx.x;
    w[tid] = attn[b * T_ + chunk * 256 + tid];
    __syncthreads();
    const int r = tid >> 6;            // 0..3 (row within 4-row step)
    const int c = tid & 63;            // float4 column
    const float* vb = values + (size_t)b * T_ * D_ + (size_t)chunk * 256 * D_;
    floatx4 acc = {0.f, 0.f, 0.f, 0.f};
#pragma unroll 4
    for (int i = 0; i < 64; ++i) {
        const int t = i * 4 + r;
        floatx4 vv = *(const floatx4*)(vb + t * D_ + c * 4);
        acc += vv * w[t];
    }
    atomicAdd(&ctx[b * D_ + c * 4 + 0], acc.x);
    atomicAdd(&ctx[b * D_ + c * 4 + 1], acc.y);
    atomicAdd(&ctx[b * D_ + c * 4 + 2], acc.z);
    atomicAdd(&ctx[b * D_ + c * 4 + 3], acc.w);
}

extern "C" void kernel_launch(void* const* d_in, const int* in_sizes, int n_in,
                              void* d_out, int out_size, void* d_ws, size_t ws_size,
                              hipStream_t stream) {
    const float* query  = (const float*)d_in[0];
    const float* values = (const float*)d_in[1];
    const float* W1_w   = (const float*)d_in[2];
    const float* W1_b   = (const float*)d_in[3];
    const float* W2_w   = (const float*)d_in[4];
    const float* W2_b   = (const float*)d_in[5];
    const float* V_w    = (const float*)d_in[6];
    // d_in[7] = V_b: softmax is shift-invariant -> no effect on either output.

    float* out  = (float*)d_out;
    float* ctx  = out;                  // [B, D]
    float* attn = out + B_ * D_;        // [B, T]

    char* ws = (char*)d_ws;
    float*     qb     = (float*)ws;                              // B*U fp32   (64 KB)
    _Float16*  w2t    = (_Float16*)(ws + 65536);                 // U*D fp16   (128 KB)
    float*     scores = (float*)(ws + 65536 + 131072);           // B*T fp32   (512 KB)

    hipMemsetAsync(ctx, 0, B_ * D_ * sizeof(float), stream);     // context accumulated via atomics
    qproj_kernel  <<<dim3(B_),        dim3(256), 0, stream>>>(query, W1_w, W1_b, W2_b, qb);
    w2t_kernel    <<<dim3(64),        dim3(256), 0, stream>>>(W2_w, w2t);
    score_kernel  <<<dim3(T_/BM, B_), dim3(256), 0, stream>>>(values, w2t, qb, V_w, scores);
    softmax_kernel<<<dim3(B_),        dim3(256), 0, stream>>>(scores, attn);
    context_kernel<<<dim3(8, B_),     dim3(256), 0, stream>>>(values, attn, ctx);
}

// Round 2
// 241.634 us; speedup vs baseline: 1.1358x; 1.1358x over previous
//
#include <hip/hip_runtime.h>
#include <hip/hip_fp16.h>
#include <stdint.h>

#define B_ 64
#define T_ 2048
#define D_ 256
#define U_ 256
#define BT 256            // T rows per score_ctx block
#define NT (BT / 16)      // 16 tiles of 16 rows
#define TC (T_ / BT)      // 8 chunks per batch

typedef _Float16 half8  __attribute__((ext_vector_type(8)));
typedef float    floatx4 __attribute__((ext_vector_type(4)));

typedef const __attribute__((address_space(1))) void cg_void;   // global src for DMA
typedef __attribute__((address_space(3))) void       ls_void;   // LDS dst for DMA

// ---------------- Kernel 1: qb[b,u] = query[b]·W1[:,u] + W1_b[u] + W2_b[u] ----------------
__global__ void qproj_kernel(const float* __restrict__ query,
                             const float* __restrict__ W1_w,
                             const float* __restrict__ W1_b,
                             const float* __restrict__ W2_b,
                             float* __restrict__ qb) {
    __shared__ float qrow[D_];
    const int b = blockIdx.x;
    const int u = threadIdx.x;           // blockDim.x == 256 == U_
    qrow[u] = query[b * D_ + u];
    __syncthreads();
    float acc = W1_b[u] + W2_b[u];
#pragma unroll 8
    for (int d = 0; d < D_; ++d)
        acc += qrow[d] * W1_w[d * U_ + u];   // coalesced over u
    qb[b * U_ + u] = acc;
}

// ---------------- Kernel 2: w2t[u,d] = (fp16) W2[d,u] ----------------
__global__ void w2t_kernel(const float* __restrict__ W2_w, _Float16* __restrict__ w2t) {
    __shared__ float tile[32][33];
    const int tu = blockIdx.x & 7;       // u tile
    const int td = blockIdx.x >> 3;      // d tile
    const int c  = threadIdx.x & 31;
    const int r0 = threadIdx.x >> 5;     // 0..7
#pragma unroll
    for (int i = 0; i < 4; ++i) {
        int r = r0 + i * 8;
        tile[r][c] = W2_w[(td * 32 + r) * U_ + tu * 32 + c];   // coalesced over c(=u)
    }
    __syncthreads();
#pragma unroll
    for (int i = 0; i < 4; ++i) {
        int r = r0 + i * 8;              // u within tile
        w2t[(tu * 32 + r) * D_ + td * 32 + c] = (_Float16)tile[c][r];  // coalesced over c(=d)
    }
}

// ---------------- Kernel 3 (fused): scores + online-softmax partial context ----------------
// ONE pass over values. Grid (TC, B), 256 threads = 4 waves; wave w owns U-chunk [w*64,w*64+64)
// with W2 register-stationary (128 VGPR/lane). fp32 value tiles staged async via
// global_load_lds(16B) into a double-buffered, XOR-swizzled LDS layout:
//   16B chunk (row, cc) lives at LDS chunk row*64 + (cc ^ (row&7)).
//   - DMA writes: lane i -> lds chunk row*64+i (contiguous, conflict-free); lane i's SOURCE
//     is global chunk cc = i ^ (row&7) (full 1KB row covered -> coalesced).
//   - MFMA A b128 reads: bank-group (quad*2+b) ^ (n16&7) -> 8 lanes/group, balanced.
//   - Context column reads: 2 lanes/bank -> free.
// Per tile: MFMA -> tanh·V_w partial -> cross-wave sum -> online m/l update (wave0 lanes 0..15)
// -> all threads rescale + accumulate c[d=tid]. Block writes partial (c[256], m, l).
__launch_bounds__(256, 2)
__global__ void score_ctx_kernel(const float* __restrict__ values,
                                 const _Float16* __restrict__ w2t,
                                 const float* __restrict__ qb,
                                 const float* __restrict__ V_w,
                                 float* __restrict__ scores,
                                 float* __restrict__ pctx,
                                 float* __restrict__ pml) {
    __shared__ __align__(16) float buf[2][16 * D_];   // 2 x 16KB fp32 tiles
    __shared__ float s_part[4][16];
    __shared__ float wbuf[16];
    __shared__ float alphabuf;

    const int b     = blockIdx.y;
    const int chunk = blockIdx.x;
    const int tid   = threadIdx.x;
    const int wave  = tid >> 6;
    const int lane  = tid & 63;
    const int n16   = lane & 15;
    const int quad  = lane >> 4;
    const int u0    = wave * 64;

    // --- W2 B-fragments, register-stationary (verified layout from R1) ---
    half8 bfrag[4][8];
#pragma unroll
    for (int ut = 0; ut < 4; ++ut) {
        const int u = u0 + ut * 16 + n16;
#pragma unroll
        for (int k = 0; k < 8; ++k)
            bfrag[ut][k] = *(const half8*)(w2t + u * D_ + k * 32 + quad * 8);
    }
    float qbv[4], vwv[4];
#pragma unroll
    for (int ut = 0; ut < 4; ++ut) {
        const int u = u0 + ut * 16 + n16;
        qbv[ut] = qb[b * U_ + u];
        vwv[ut] = V_w[u];
    }

    const float* vbase = values + (size_t)b * T_ * D_ + (size_t)chunk * BT * D_;

    float c     = 0.f;       // context accumulator: this thread owns d = tid
    float m_run = -1e30f;    // live in lanes 0..15 of wave 0 (consistent copies)
    float l_run = 0.f;

    // async stage of one 16-row tile: 16 wave-level DMA ops, 4 per wave
    auto stage = [&](int tile, int bi) {
        const float* src = vbase + tile * 16 * D_;
#pragma unroll
        for (int i = 0; i < 4; ++i) {
            const int r = i * 4 + wave;                          // wave-uniform row
            const float* g = src + r * D_ + ((lane ^ (r & 7)) << 2);
            float* l = &buf[bi][r * D_];                         // wave-uniform LDS base
            __builtin_amdgcn_global_load_lds((cg_void*)g, (ls_void*)l, 16, 0, 0);
        }
    };

    stage(0, 0);

    for (int tile = 0; tile < NT; ++tile) {
        const int cur = tile & 1;
        __syncthreads();                          // tile 'cur' staged; prev accumulate done
        if (tile + 1 < NT) stage(tile + 1, cur ^ 1);

        // --- MFMA: Vp[16 x 64chunk], A from swizzled fp32 LDS, cvt in regs ---
        floatx4 acc[4] = {};
        const float* rowbase = &buf[cur][n16 * D_];
        const int swz = n16 & 7;
#pragma unroll
        for (int k = 0; k < 8; ++k) {
            const int c0 = k * 8 + quad * 2;
            floatx4 q0 = *(const floatx4*)(rowbase + (((c0    ) ^ swz) << 2));
            floatx4 q1 = *(const floatx4*)(rowbase + (((c0 + 1) ^ swz) << 2));
            half8 a;
            a[0] = (_Float16)q0.x; a[1] = (_Float16)q0.y;
            a[2] = (_Float16)q0.z; a[3] = (_Float16)q0.w;
            a[4] = (_Float16)q1.x; a[5] = (_Float16)q1.y;
            a[6] = (_Float16)q1.z; a[7] = (_Float16)q1.w;
#pragma unroll
            for (int ut = 0; ut < 4; ++ut)
                acc[ut] = __builtin_amdgcn_mfma_f32_16x16x32_f16(a, bfrag[ut][k], acc[ut], 0, 0, 0);
        }

        // --- epilogue: tanh + dot with V_w, reduce over u (n16) ---
        float part[4];
#pragma unroll
        for (int r = 0; r < 4; ++r) {
            float s = 0.f;
#pragma unroll
            for (int ut = 0; ut < 4; ++ut) {
                float x  = acc[ut][r] + qbv[ut];
                float e  = __expf(2.f * x);
                float th = 1.f - __fdividef(2.f, e + 1.f);   // tanh(x)
                s += th * vwv[ut];
            }
            part[r] = s;
        }
#pragma unroll
        for (int m = 1; m < 16; m <<= 1)
#pragma unroll
            for (int r = 0; r < 4; ++r)
                part[r] += __shfl_xor(part[r], m, 16);
        if (n16 == 0)
#pragma unroll
            for (int r = 0; r < 4; ++r)
                s_part[wave][quad * 4 + r] = part[r];
        __syncthreads();

        // --- online softmax update (wave 0, lanes 0..15; all compute identical m/l) ---
        if (tid < 16) {
            float s = s_part[0][tid] + s_part[1][tid] + s_part[2][tid] + s_part[3][tid];
            scores[b * T_ + chunk * BT + tile * 16 + tid] = s;   // raw score for attn pass
            float mt = s;
#pragma unroll
            for (int m = 1; m < 16; m <<= 1) mt = fmaxf(mt, __shfl_xor(mt, m, 16));
            const float m_new = fmaxf(m_run, mt);
            const float alpha = __expf(m_run - m_new);
            const float w     = __expf(s - m_new);
            float ls = w;
#pragma unroll
            for (int m = 1; m < 16; m <<= 1) ls += __shfl_xor(ls, m, 16);
            l_run = l_run * alpha + ls;
            m_run = m_new;
            wbuf[tid] = w;
            if (tid == 0) alphabuf = alpha;
        }
        __syncthreads();

        // --- context accumulate: c[d=tid] = c*alpha + sum_t w_t * values[t][tid] ---
        const float alpha = alphabuf;
        c *= alpha;
        const int ccx = tid >> 2, lo = tid & 3;
#pragma unroll
        for (int t = 0; t < 16; ++t) {
            float v = buf[cur][t * D_ + (((ccx) ^ (t & 7)) << 2) + lo];
            c += wbuf[t] * v;
        }
    }

    pctx[(b * TC + chunk) * D_ + tid] = c;
    if (tid == 0) {
        pml[(b * TC + chunk) * 2 + 0] = m_run;
        pml[(b * TC + chunk) * 2 + 1] = l_run;
    }
}

// ---------------- Kernel 4: combine partials -> ctx, attn ----------------
__global__ void finalize_kernel(const float* __restrict__ pctx,
                                const float* __restrict__ pml,
                                const float* __restrict__ scores,
                                float* __restrict__ ctx,
                                float* __restrict__ attn) {
    const int b = blockIdx.x, tid = threadIdx.x;   // 256 threads
    float m[TC], l[TC], e[TC];
    float M = -1e30f;
#pragma unroll
    for (int i = 0; i < TC; ++i) {
        m[i] = pml[(b * TC + i) * 2 + 0];
        l[i] = pml[(b * TC + i) * 2 + 1];
        M = fmaxf(M, m[i]);
    }
    float L = 0.f;
#pragma unroll
    for (int i = 0; i < TC; ++i) { e[i] = __expf(m[i] - M); L += l[i] * e[i]; }
    float s = 0.f;
#pragma unroll
    for (int i = 0; i < TC; ++i) s += pctx[(b * TC + i) * D_ + tid] * e[i];
    const float invL = 1.f / L;
    ctx[b * D_ + tid] = s * invL;
#pragma unroll
    for (int j = 0; j < T_ / 256; ++j) {
        const int t = j * 256 + tid;
        attn[b * T_ + t] = __expf(scores[b * T_ + t] - M) * invL;
    }
}

extern "C" void kernel_launch(void* const* d_in, const int* in_sizes, int n_in,
                              void* d_out, int out_size, void* d_ws, size_t ws_size,
                              hipStream_t stream) {
    const float* query  = (const float*)d_in[0];
    const float* values = (const float*)d_in[1];
    const float* W1_w   = (const float*)d_in[2];
    const float* W1_b   = (const float*)d_in[3];
    const float* W2_w   = (const float*)d_in[4];
    const float* W2_b   = (const float*)d_in[5];
    const float* V_w    = (const float*)d_in[6];
    // d_in[7] = V_b: softmax is shift-invariant -> no effect on either output.

    float* out  = (float*)d_out;
    float* ctx  = out;                  // [B, D]
    float* attn = out + B_ * D_;        // [B, T]

    char* ws = (char*)d_ws;
    float*    qb     = (float*)ws;                               // B*U fp32     (64 KB)
    _Float16* w2t    = (_Float16*)(ws + (64 << 10));             // U*D fp16     (128 KB)
    float*    scores = (float*)(ws + (192 << 10));               // B*T fp32     (512 KB)
    float*    pctx   = (float*)(ws + (704 << 10));               // B*TC*D fp32  (512 KB)
    float*    pml    = (float*)(ws + (1216 << 10));              // B*TC*2 fp32  (4 KB)

    qproj_kernel    <<<dim3(B_),      dim3(256), 0, stream>>>(query, W1_w, W1_b, W2_b, qb);
    w2t_kernel      <<<dim3(64),      dim3(256), 0, stream>>>(W2_w, w2t);
    score_ctx_kernel<<<dim3(TC, B_),  dim3(256), 0, stream>>>(values, w2t, qb, V_w, scores, pctx, pml);
    finalize_kernel <<<dim3(B_),      dim3(256), 0, stream>>>(pctx, pml, scores, ctx, attn);
}